// Round 8
// baseline (219.021 us; speedup 1.0000x reference)
//
#include <hip/hip_runtime.h>
#include <hip/hip_cooperative_groups.h>
#include <math.h>

namespace cg = cooperative_groups;

#define N_PTS 100000
#define KDIM 128
#define CDIM 128          // IN_C == OUT_C == 128
#define TILE_N 64
#define NB1 ((N_PTS + TILE_N - 1) / TILE_N)   // 1563 C1 tiles
#define CT 4                                   // tiles per kCC block
#define CGRID ((NB1 + CT - 1) / CT)            // 391 cooperative blocks

typedef short s16x8 __attribute__((ext_vector_type(8)));
typedef float f32x4 __attribute__((ext_vector_type(4)));

// round-to-nearest-even float -> bf16 bits
static __device__ __forceinline__ unsigned short f2bf(float f) {
    unsigned int u = __float_as_uint(f);
    unsigned int r = (u + 0x7FFFu + ((u >> 16) & 1u)) >> 16;
    return (unsigned short)r;
}
static __device__ __forceinline__ float bf2f(unsigned short h) {
    return __uint_as_float(((unsigned int)h) << 16);
}

// truncation hi/lo split (cheap; residual error ~2^-16 relative)
static __device__ __forceinline__ void split_trunc(float v, unsigned short& hi, unsigned short& lo) {
    unsigned int u = __float_as_uint(v);
    unsigned int uh = u & 0xFFFF0000u;
    float lf = v - __uint_as_float(uh);
    hi = (unsigned short)(u >> 16);
    lo = (unsigned short)(__float_as_uint(lf) >> 16);
}

// ---------------- Kernel A (v10, fragment-direct, barrier-free):
// partials[b][k][i] = sum_{n in chunk} U[n,k]*x[n,i]
// Each lane loads its MFMA fragment elements straight from global; intra-block
// redundancy is absorbed by L2 (verified R7: FETCH ~= 51 MB = compulsory).
__global__ __launch_bounds__(512) void kA(const float* __restrict__ U,
                                          const float* __restrict__ x,
                                          float* __restrict__ partials,
                                          int chunk) {
    const int tid = threadIdx.x;
    const int b = blockIdx.x;
    const int n_begin = b * chunk;
    const int n_end = min(N_PTS, n_begin + chunk);
    const int lane = tid & 63;
    const int w = tid >> 6;             // wave 0..7
    const int mtb = (w & 3) * 2;        // k-tile base: 2 tiles
    const int ntb = (w >> 2) * 4;       // i-tile base: 4 tiles
    const int quad = lane >> 4;
    const int nl = lane & 15;

    f32x4 acc[2][4];
#pragma unroll
    for (int mi = 0; mi < 2; ++mi)
#pragma unroll
        for (int ni = 0; ni < 4; ++ni) acc[mi][ni] = (f32x4)(0.0f);

    for (int r0 = n_begin; r0 < n_end; r0 += 32) {
        const int rb = r0 + 8 * quad;   // this lane's first row of the chunk
        s16x8 ah[2], al[2];
        {
            const float* ubase = U + (size_t)rb * 128 + mtb * 16 + nl;
#pragma unroll
            for (int mi = 0; mi < 2; ++mi) {
                float v[8];
#pragma unroll
                for (int j = 0; j < 8; ++j) v[j] = ubase[(size_t)j * 128 + mi * 16];
                s16x8 hh, ll;
#pragma unroll
                for (int j = 0; j < 8; ++j) {
                    unsigned short h, l;
                    split_trunc(v[j], h, l);
                    hh[j] = (short)h; ll[j] = (short)l;
                }
                ah[mi] = hh; al[mi] = ll;
            }
        }
        {
            const float* xbase = x + (size_t)rb * 128 + ntb * 16 + nl;
#pragma unroll
            for (int ni = 0; ni < 4; ++ni) {
                float v[8];
#pragma unroll
                for (int j = 0; j < 8; ++j) v[j] = xbase[(size_t)j * 128 + ni * 16];
                s16x8 bh, bl;
#pragma unroll
                for (int j = 0; j < 8; ++j) {
                    unsigned short h, l;
                    split_trunc(v[j], h, l);
                    bh[j] = (short)h; bl[j] = (short)l;
                }
#pragma unroll
                for (int mi = 0; mi < 2; ++mi) {
                    acc[mi][ni] = __builtin_amdgcn_mfma_f32_16x16x32_bf16(ah[mi], bh, acc[mi][ni], 0, 0, 0);
                    acc[mi][ni] = __builtin_amdgcn_mfma_f32_16x16x32_bf16(al[mi], bh, acc[mi][ni], 0, 0, 0);
                    acc[mi][ni] = __builtin_amdgcn_mfma_f32_16x16x32_bf16(ah[mi], bl, acc[mi][ni], 0, 0, 0);
                }
            }
        }
    }

    float* p = partials + (size_t)b * 16384;
#pragma unroll
    for (int mi = 0; mi < 2; ++mi) {
#pragma unroll
        for (int reg = 0; reg < 4; ++reg) {
            int k = (mtb + mi) * 16 + quad * 4 + reg;
#pragma unroll
            for (int ni = 0; ni < 4; ++ni) {
                int i = (ntb + ni) * 16 + nl;
                p[k * 128 + i] = acc[mi][ni][reg];
            }
        }
    }
}

// ---------------- Kernel A2a (v2, float4): partial2[s][j..j+3] = sum over s-slice of b
__global__ __launch_bounds__(256) void kA2a(const float* __restrict__ partials,
                                            float* __restrict__ partial2, int nA) {
    const int jc = blockIdx.x >> 3;                 // 16 j-chunks of 1024
    const int s = blockIdx.x & 7;
    const int j = jc * 1024 + threadIdx.x * 4;
    const int per = (nA + 7) >> 3;
    int b = s * per;
    const int be = min(b + per, nA);
    f32x4 a0 = (f32x4)(0.0f), a1 = (f32x4)(0.0f);
    for (; b + 2 <= be; b += 2) {
        a0 += *(const f32x4*)&partials[(size_t)(b + 0) * 16384 + j];
        a1 += *(const f32x4*)&partials[(size_t)(b + 1) * 16384 + j];
    }
    for (; b < be; ++b) a0 += *(const f32x4*)&partials[(size_t)b * 16384 + j];
    *(f32x4*)&partial2[(size_t)s * 16384 + j] = a0 + a1;
}

// ---------------- Kernel B: mixed[o][k] = sum_i coeffs[o][k][i]*spec[k][i]
__global__ __launch_bounds__(256) void kB(const float* __restrict__ coeffs,
                                          const float* __restrict__ partial2,
                                          unsigned short* __restrict__ afrag_hi,
                                          unsigned short* __restrict__ afrag_lo) {
    int wave = (blockIdx.x * 256 + threadIdx.x) >> 6;   // [0, 16384)
    int lane = threadIdx.x & 63;
    int o = wave >> 7;
    int k = wave & 127;
    const int j = k * 128 + lane * 2;
    float2 p0 = *(const float2*)&partial2[j];
    float2 p1 = *(const float2*)&partial2[16384 + j];
    float2 p2 = *(const float2*)&partial2[2 * 16384 + j];
    float2 p3 = *(const float2*)&partial2[3 * 16384 + j];
    float2 p4 = *(const float2*)&partial2[4 * 16384 + j];
    float2 p5 = *(const float2*)&partial2[5 * 16384 + j];
    float2 p6 = *(const float2*)&partial2[6 * 16384 + j];
    float2 p7 = *(const float2*)&partial2[7 * 16384 + j];
    float sx = ((p0.x + p1.x) + (p2.x + p3.x)) + ((p4.x + p5.x) + (p6.x + p7.x));
    float sy = ((p0.y + p1.y) + (p2.y + p3.y)) + ((p4.y + p5.y) + (p6.y + p7.y));
    float2 c2 = *(const float2*)&coeffs[((size_t)o * 128 + k) * 128 + lane * 2];
    float v = c2.x * sx + c2.y * sy;
#pragma unroll
    for (int s = 32; s >= 1; s >>= 1) v += __shfl_xor(v, s);
    if (lane == 0) {
        unsigned short hi = f2bf(v);
        unsigned short lo = f2bf(v - bf2f(hi));
        int idx = ((o >> 4) * 4 + (k >> 5)) * 512 + (((k >> 3) & 3) * 16 + (o & 15)) * 8 + (k & 7);
        afrag_hi[idx] = hi;
        afrag_lo[idx] = lo;
    }
}

// ---------------- kCC: cooperative fused C-phase.
// Phase 1: each block computes CT=4 s-tiles (64n x 128o each), keeps ALL
//   accumulators in registers, writes only per-tile (m,l).  grid.sync()
// Phase 2: blocks 0..127 reduce global (M, 1/L) for o=blockIdx (kC2 math;
//   L==1.0 bit-exact here since softmax is one-hot).        grid.sync()
// Phase 3: normalize register-resident s and write out ONCE:
//   out = exp(s - m_b) * [exp(m_b - M) * invL]   (R4-proven formula)
// Eliminates the 51 MB unnormalized-out write + 102 MB kC3 RMW.
__global__ __launch_bounds__(512, 4) void kCC(const float* __restrict__ U,
                                              const unsigned short* __restrict__ afrag_hi,
                                              const unsigned short* __restrict__ afrag_lo,
                                              float* __restrict__ m_part,
                                              float* __restrict__ l_part,
                                              float* __restrict__ ML,   // [0..127]=M, [128..255]=invL
                                              float* __restrict__ out) {
    cg::grid_group gg = cg::this_grid();
    __shared__ unsigned short Bh[8192];
    __shared__ unsigned short Bl[8192];
    __shared__ float sm[512];
    const int tid = threadIdx.x;
    const int lane = tid & 63;
    const int w = tid >> 6;
    const int quad = lane >> 4;
    const int nl = lane & 15;

    f32x4 acc[CT][4];     // raw s, register-resident across the grid syncs
    float mbv[CT][4];

    // ---------------- phase 1
#pragma unroll
    for (int t = 0; t < CT; ++t) {
        const int b = blockIdx.x * CT + t;     // block-uniform
        if (b < NB1) {
            const int n0 = b * TILE_N;
            // stage U -> bf16 hi/lo B-fragments in LDS (kC1's proven code)
            {
                const int sn = tid & 63;
                const int k8b = tid >> 6;
                const int gn = n0 + sn;
#pragma unroll
                for (int r = 0; r < 2; ++r) {
                    const int k0 = (k8b + r * 8) * 8;
                    float4 f0 = make_float4(0, 0, 0, 0), f1 = make_float4(0, 0, 0, 0);
                    if (gn < N_PTS) {
                        f0 = *(const float4*)&U[(size_t)gn * 128 + k0];
                        f1 = *(const float4*)&U[(size_t)gn * 128 + k0 + 4];
                    }
                    float vv[8] = {f0.x, f0.y, f0.z, f0.w, f1.x, f1.y, f1.z, f1.w};
                    s16x8 hh, ll;
#pragma unroll
                    for (int jj = 0; jj < 8; ++jj) {
                        unsigned short h, l;
                        split_trunc(vv[jj], h, l);
                        hh[jj] = (short)h;
                        ll[jj] = (short)l;
                    }
                    const int T = (k0 >> 5) * 4 + (sn >> 4);
                    const int g = T * 64 + ((k0 >> 3) & 3) * 16 + ((sn & 15) ^ (T & 3));
                    *(s16x8*)&Bh[g * 8] = hh;
                    *(s16x8*)&Bl[g * 8] = ll;
                }
            }
            __syncthreads();

#pragma unroll
            for (int nt = 0; nt < 4; ++nt) acc[t][nt] = (f32x4)(0.0f);

#pragma unroll
            for (int kc = 0; kc < 4; ++kc) {
                // A-fragments loaded per-kc (keeps live VGPRs low; L2-hot)
                size_t aoff = (size_t)(w * 4 + kc) * 512 + lane * 8;
                s16x8 Ah = *(const s16x8*)(afrag_hi + aoff);
                s16x8 Al = *(const s16x8*)(afrag_lo + aoff);
#pragma unroll
                for (int nt = 0; nt < 4; ++nt) {
                    const int T = kc * 4 + nt;
                    const int g = T * 64 + quad * 16 + (nl ^ (T & 3));
                    s16x8 bh = *(s16x8*)&Bh[g * 8];
                    s16x8 bl = *(s16x8*)&Bl[g * 8];
                    acc[t][nt] = __builtin_amdgcn_mfma_f32_16x16x32_bf16(Ah, bh, acc[t][nt], 0, 0, 0);
                    acc[t][nt] = __builtin_amdgcn_mfma_f32_16x16x32_bf16(Al, bh, acc[t][nt], 0, 0, 0);
                    acc[t][nt] = __builtin_amdgcn_mfma_f32_16x16x32_bf16(Ah, bl, acc[t][nt], 0, 0, 0);
                }
            }
            __syncthreads();   // LDS free for next tile

            // OOB guard
#pragma unroll
            for (int nt = 0; nt < 4; ++nt) {
                if (n0 + nt * 16 + nl >= N_PTS) {
#pragma unroll
                    for (int reg = 0; reg < 4; ++reg) acc[t][nt][reg] = -3.4e38f;
                }
            }
            // per-o max over 64 n
            float mb[4];
#pragma unroll
            for (int reg = 0; reg < 4; ++reg)
                mb[reg] = fmaxf(fmaxf(acc[t][0][reg], acc[t][1][reg]),
                                fmaxf(acc[t][2][reg], acc[t][3][reg]));
#pragma unroll
            for (int s = 1; s < 16; s <<= 1) {
#pragma unroll
                for (int reg = 0; reg < 4; ++reg) mb[reg] = fmaxf(mb[reg], __shfl_xor(mb[reg], s));
            }
#pragma unroll
            for (int reg = 0; reg < 4; ++reg) mbv[t][reg] = mb[reg];

            // per-o sum of exp (OOB lanes contribute exp(-huge)=0)
            float ls[4];
#pragma unroll
            for (int reg = 0; reg < 4; ++reg) {
                float e0 = __expf(acc[t][0][reg] - mb[reg]);
                float e1 = __expf(acc[t][1][reg] - mb[reg]);
                float e2 = __expf(acc[t][2][reg] - mb[reg]);
                float e3 = __expf(acc[t][3][reg] - mb[reg]);
                ls[reg] = (e0 + e1) + (e2 + e3);
            }
#pragma unroll
            for (int s = 1; s < 16; s <<= 1) {
#pragma unroll
                for (int reg = 0; reg < 4; ++reg) ls[reg] += __shfl_xor(ls[reg], s);
            }
            if (nl == 0) {
#pragma unroll
                for (int reg = 0; reg < 4; ++reg) {
                    int o = w * 16 + quad * 4 + reg;
                    m_part[(size_t)o * NB1 + b] = mb[reg];
                    l_part[(size_t)o * NB1 + b] = ls[reg];
                }
            }
        } else {
#pragma unroll
            for (int nt = 0; nt < 4; ++nt) acc[t][nt] = (f32x4)(0.0f);
#pragma unroll
            for (int reg = 0; reg < 4; ++reg) mbv[t][reg] = 0.0f;
        }
    }

    gg.sync();

    // ---------------- phase 2: blocks 0..127 compute global (M, invL) for o=blockIdx
    if (blockIdx.x < 128) {
        const int o = blockIdx.x;
        const float* __restrict__ mp = m_part + (size_t)o * NB1;
        const float* __restrict__ lp = l_part + (size_t)o * NB1;
        float m = -3.4e38f;
        for (int b2 = tid; b2 < NB1; b2 += 512) m = fmaxf(m, mp[b2]);
        sm[tid] = m;
        __syncthreads();
        for (int s = 256; s >= 1; s >>= 1) {
            if (tid < s) sm[tid] = fmaxf(sm[tid], sm[tid + s]);
            __syncthreads();
        }
        m = sm[0];
        __syncthreads();
        float l = 0.0f;
        for (int b2 = tid; b2 < NB1; b2 += 512) l += lp[b2] * __expf(mp[b2] - m);
        sm[tid] = l;
        __syncthreads();
        for (int s = 256; s >= 1; s >>= 1) {
            if (tid < s) sm[tid] += sm[tid + s];
            __syncthreads();
        }
        if (tid == 0) {
            ML[o] = m;
            ML[128 + o] = 1.0f / sm[0];
        }
    }

    gg.sync();

    // ---------------- phase 3: normalize register-resident s, write out once
#pragma unroll
    for (int t = 0; t < CT; ++t) {
        const int b = blockIdx.x * CT + t;
        if (b < NB1) {
            const int n0 = b * TILE_N;
            float fac[4];
#pragma unroll
            for (int reg = 0; reg < 4; ++reg) {
                int o = w * 16 + quad * 4 + reg;
                fac[reg] = __expf(mbv[t][reg] - ML[o]) * ML[128 + o];
            }
#pragma unroll
            for (int nt = 0; nt < 4; ++nt) {
                f32x4 v;
#pragma unroll
                for (int reg = 0; reg < 4; ++reg)
                    v[reg] = __expf(acc[t][nt][reg] - mbv[t][reg]) * fac[reg];
                int gn = n0 + nt * 16 + nl;
                if (gn < N_PTS)
                    *(f32x4*)&out[(size_t)gn * 128 + w * 16 + quad * 4] = v;
            }
        }
    }
}

// ---------------- Fallback path (proven R0/R2 structure) ----------------
__global__ __launch_bounds__(512) void kC1(const float* __restrict__ U,
                                           const unsigned short* __restrict__ afrag_hi,
                                           const unsigned short* __restrict__ afrag_lo,
                                           float* __restrict__ out,
                                           float* __restrict__ m_part,
                                           float* __restrict__ l_part) {
    __shared__ unsigned short Bh[8192];
    __shared__ unsigned short Bl[8192];
    const int tid = threadIdx.x;
    const int b = blockIdx.x;
    const int n0 = b * TILE_N;
    const int lane = tid & 63;
    const int w = tid >> 6;
    const int quad = lane >> 4;
    const int nl = lane & 15;

    {
        const int sn = tid & 63;
        const int k8b = tid >> 6;
        const int gn = n0 + sn;
#pragma unroll
        for (int r = 0; r < 2; ++r) {
            const int k0 = (k8b + r * 8) * 8;
            float4 f0 = make_float4(0, 0, 0, 0), f1 = make_float4(0, 0, 0, 0);
            if (gn < N_PTS) {
                f0 = *(const float4*)&U[(size_t)gn * 128 + k0];
                f1 = *(const float4*)&U[(size_t)gn * 128 + k0 + 4];
            }
            float vv[8] = {f0.x, f0.y, f0.z, f0.w, f1.x, f1.y, f1.z, f1.w};
            s16x8 hh, ll;
#pragma unroll
            for (int jj = 0; jj < 8; ++jj) {
                unsigned short h, l;
                split_trunc(vv[jj], h, l);
                hh[jj] = (short)h;
                ll[jj] = (short)l;
            }
            const int T = (k0 >> 5) * 4 + (sn >> 4);
            const int g = T * 64 + ((k0 >> 3) & 3) * 16 + ((sn & 15) ^ (T & 3));
            *(s16x8*)&Bh[g * 8] = hh;
            *(s16x8*)&Bl[g * 8] = ll;
        }
    }

    s16x8 Ah[4], Al[4];
#pragma unroll
    for (int kc = 0; kc < 4; ++kc) {
        size_t aoff = (size_t)(w * 4 + kc) * 512 + lane * 8;
        Ah[kc] = *(const s16x8*)(afrag_hi + aoff);
        Al[kc] = *(const s16x8*)(afrag_lo + aoff);
    }

    __syncthreads();

    f32x4 acc[4];
#pragma unroll
    for (int nt = 0; nt < 4; ++nt) acc[nt] = (f32x4)(0.0f);

#pragma unroll
    for (int kc = 0; kc < 4; ++kc) {
#pragma unroll
        for (int nt = 0; nt < 4; ++nt) {
            const int T = kc * 4 + nt;
            const int g = T * 64 + quad * 16 + (nl ^ (T & 3));
            s16x8 bh = *(s16x8*)&Bh[g * 8];
            s16x8 bl = *(s16x8*)&Bl[g * 8];
            acc[nt] = __builtin_amdgcn_mfma_f32_16x16x32_bf16(Ah[kc], bh, acc[nt], 0, 0, 0);
            acc[nt] = __builtin_amdgcn_mfma_f32_16x16x32_bf16(Al[kc], bh, acc[nt], 0, 0, 0);
            acc[nt] = __builtin_amdgcn_mfma_f32_16x16x32_bf16(Ah[kc], bl, acc[nt], 0, 0, 0);
        }
    }

#pragma unroll
    for (int nt = 0; nt < 4; ++nt) {
        if (n0 + nt * 16 + nl >= N_PTS) {
#pragma unroll
            for (int reg = 0; reg < 4; ++reg) acc[nt][reg] = -3.4e38f;
        }
    }

    float mb[4];
#pragma unroll
    for (int reg = 0; reg < 4; ++reg)
        mb[reg] = fmaxf(fmaxf(acc[0][reg], acc[1][reg]), fmaxf(acc[2][reg], acc[3][reg]));
#pragma unroll
    for (int s = 1; s < 16; s <<= 1) {
#pragma unroll
        for (int reg = 0; reg < 4; ++reg) mb[reg] = fmaxf(mb[reg], __shfl_xor(mb[reg], s));
    }

#pragma unroll
    for (int nt = 0; nt < 4; ++nt) {
#pragma unroll
        for (int reg = 0; reg < 4; ++reg) acc[nt][reg] = __expf(acc[nt][reg] - mb[reg]);
        int gn = n0 + nt * 16 + nl;
        if (gn < N_PTS)
            *(f32x4*)&out[(size_t)gn * 128 + w * 16 + quad * 4] = acc[nt];
    }

    float ls[4];
#pragma unroll
    for (int reg = 0; reg < 4; ++reg)
        ls[reg] = ((acc[0][reg] + acc[1][reg]) + (acc[2][reg] + acc[3][reg]));
#pragma unroll
    for (int s = 1; s < 16; s <<= 1) {
#pragma unroll
        for (int reg = 0; reg < 4; ++reg) ls[reg] += __shfl_xor(ls[reg], s);
    }

    if (nl == 0) {
#pragma unroll
        for (int reg = 0; reg < 4; ++reg) {
            int o = w * 16 + quad * 4 + reg;
            m_part[(size_t)o * NB1 + b] = mb[reg];
            l_part[(size_t)o * NB1 + b] = ls[reg];
        }
    }
}

__global__ __launch_bounds__(256) void kC2(const float* __restrict__ m_part,
                                           const float* __restrict__ l_part,
                                           float* __restrict__ scale) {
    const int o = blockIdx.x;
    const int tid = threadIdx.x;
    const float* __restrict__ mp = m_part + (size_t)o * NB1;
    const float* __restrict__ lp = l_part + (size_t)o * NB1;
    __shared__ float sm[256];
    float m = -3.4e38f;
    for (int b = tid; b < NB1; b += 256) m = fmaxf(m, mp[b]);
    sm[tid] = m;
    __syncthreads();
    for (int s = 128; s >= 1; s >>= 1) {
        if (tid < s) sm[tid] = fmaxf(sm[tid], sm[tid + s]);
        __syncthreads();
    }
    m = sm[0];
    __syncthreads();
    float l = 0.0f;
    for (int b = tid; b < NB1; b += 256)
        l += lp[b] * __expf(mp[b] - m);
    sm[tid] = l;
    __syncthreads();
    for (int s = 128; s >= 1; s >>= 1) {
        if (tid < s) sm[tid] += sm[tid + s];
        __syncthreads();
    }
    l = sm[0];
    float inv = 1.0f / l;
    for (int b = tid; b < NB1; b += 256)
        scale[(size_t)o * NB1 + b] = __expf(mp[b] - m) * inv;
}

__global__ __launch_bounds__(256) void kC3(float* __restrict__ out,
                                           const float* __restrict__ scale) {
    const int b = blockIdx.x;
    const int tid = threadIdx.x;
    __shared__ float sc[128];
    if (tid < 128) sc[tid] = scale[(size_t)tid * NB1 + b];
    __syncthreads();
    const int n0 = b * TILE_N;
#pragma unroll
    for (int r = 0; r < 8; ++r) {
        int idx = (r * 256 + tid) * 4;
        int n = idx >> 7;
        int o = idx & 127;
        int gn = n0 + n;
        if (gn < N_PTS) {
            float4 v = *(float4*)&out[(size_t)gn * 128 + o];
            v.x *= sc[o];
            v.y *= sc[o + 1];
            v.z *= sc[o + 2];
            v.w *= sc[o + 3];
            *(float4*)&out[(size_t)gn * 128 + o] = v;
        }
    }
}

extern "C" void kernel_launch(void* const* d_in, const int* in_sizes, int n_in,
                              void* d_out, int out_size, void* d_ws, size_t ws_size,
                              hipStream_t stream) {
    const float* x = (const float*)d_in[0];       // (N, 128)
    const float* U = (const float*)d_in[1];       // (N, 128)
    const float* coeffs = (const float*)d_in[2];  // (128, 128, 128)
    float* out = (float*)d_out;                   // (N, 128)

    // workspace layout (float units; keep 16B alignment for frag buffers)
    float* f = (float*)d_ws;
    float* spec = f;                                    // 16384 (unused; layout keeper)
    unsigned short* afrag_hi = (unsigned short*)(f + 16384);   // 16384 bf16 = 8192 f
    unsigned short* afrag_lo = (unsigned short*)(f + 16384 + 8192);
    float* m_part = f + 16384 + 16384;                  // 128*NB1 ([o][b])
    float* l_part = m_part + (size_t)128 * NB1;
    float* scale = l_part + (size_t)128 * NB1;          // 128*NB1 (kCC uses first 256 as M/invL)
    float* partial2 = scale + (size_t)128 * NB1;        // 8*16384
    float* partialsA = partial2 + 8 * 16384;
    (void)spec;

    size_t fixed_bytes = ((size_t)(16384 * 2) + (size_t)NB1 * 128 * 3 + (size_t)8 * 16384) * 4;
    int nA = 512;
    if (ws_size > fixed_bytes) {
        size_t avail = (ws_size - fixed_bytes) / 65536;   // 64KB per partial
        if ((size_t)nA > avail) nA = (int)avail;
    } else {
        nA = 1;
    }
    if (nA < 1) nA = 1;
    int chunk = (((N_PTS + nA - 1) / nA) + 31) & ~31;
    int nB = (N_PTS + chunk - 1) / chunk;

    kA<<<nB, 512, 0, stream>>>(U, x, partialsA, chunk);
    kA2a<<<128, 256, 0, stream>>>(partialsA, partial2, nB);
    kB<<<4096, 256, 0, stream>>>(coeffs, partial2, afrag_hi, afrag_lo);

    // fused cooperative C-phase; fall back to kC1/kC2/kC3 if unsupported
    bool coop_ok = false;
    int maxb = 0;
    if (hipOccupancyMaxActiveBlocksPerMultiprocessor(&maxb, (const void*)kCC, 512, 0) == hipSuccess &&
        (long)maxb * 256 >= CGRID) {
        void* args[] = {(void*)&U, (void*)&afrag_hi, (void*)&afrag_lo,
                        (void*)&m_part, (void*)&l_part, (void*)&scale, (void*)&out};
        if (hipLaunchCooperativeKernel((const void*)kCC, dim3(CGRID), dim3(512),
                                       args, 0, stream) == hipSuccess)
            coop_ok = true;
    }
    if (!coop_ok) {
        kC1<<<NB1, 512, 0, stream>>>(U, afrag_hi, afrag_lo, out, m_part, l_part);
        kC2<<<128, 256, 0, stream>>>(m_part, l_part, scale);
        kC3<<<NB1, 256, 0, stream>>>(out, scale);
    }
}

// Round 9
// 206.805 us; speedup vs baseline: 1.0591x; 1.0591x over previous
//
#include <hip/hip_runtime.h>
#include <math.h>

#define N_PTS 100000
#define KDIM 128
#define CDIM 128          // IN_C == OUT_C == 128
#define TILE_N 64
#define NB1 ((N_PTS + TILE_N - 1) / TILE_N)   // 1563 C1 blocks

typedef short s16x8 __attribute__((ext_vector_type(8)));
typedef float f32x4 __attribute__((ext_vector_type(4)));

// round-to-nearest-even float -> bf16 bits
static __device__ __forceinline__ unsigned short f2bf(float f) {
    unsigned int u = __float_as_uint(f);
    unsigned int r = (u + 0x7FFFu + ((u >> 16) & 1u)) >> 16;
    return (unsigned short)r;
}
static __device__ __forceinline__ float bf2f(unsigned short h) {
    return __uint_as_float(((unsigned int)h) << 16);
}

// truncation hi/lo split (cheap; residual error ~2^-16 relative)
static __device__ __forceinline__ void split_trunc(float v, unsigned short& hi, unsigned short& lo) {
    unsigned int u = __float_as_uint(v);
    unsigned int uh = u & 0xFFFF0000u;
    float lf = v - __uint_as_float(uh);
    hi = (unsigned short)(u >> 16);
    lo = (unsigned short)(__float_as_uint(lf) >> 16);
}

// ---------------- Kernel A (MFMA v4, pipelined -- R0's best-measured variant):
// partials[b][k][i] = sum_{n in chunk} U[n,k]*x[n,i]
// 512 thr = 8 waves. 32-row sub-chunks, LDS double-buffered (2 x 32 KB).
__global__ __launch_bounds__(512, 4) void kA(const float* __restrict__ U,
                                             const float* __restrict__ x,
                                             float* __restrict__ partials,
                                             int chunk) {
    // [buf][arr: 0=U_hi 1=U_lo 2=x_hi 3=x_lo][4096 u16]
    __shared__ unsigned short SB[2][4][4096];   // 64 KB total
    const int tid = threadIdx.x;
    const int b = blockIdx.x;
    const int n_begin = b * chunk;
    const int n_end = min(N_PTS, n_begin + chunk);
    const int lane = tid & 63;
    const int w = tid >> 6;             // wave 0..7
    const int mtb = (w & 3) * 2;        // k-tile base: 2 tiles
    const int ntb = (w >> 2) * 4;       // i-tile base: 4 tiles
    const int quad = lane >> 4;
    const int nl = lane & 15;

    // staging role: thread owns channel sc, row octet rq (rows rq*8..+7 of the 32-row chunk)
    const int sc = tid & 127;           // channel 0..127
    const int rq = tid >> 7;            // 0..3
    const int sgran = (sc >> 4) * 64 + rq * 16 + (sc & 15);   // conflict-free granule

    f32x4 acc[2][4];
#pragma unroll
    for (int mi = 0; mi < 2; ++mi)
#pragma unroll
        for (int ni = 0; ni < 4; ++ni) acc[mi][ni] = (f32x4)(0.0f);

    float uv[8], xv[8];

    // prologue: load + stage chunk 0
    {
        const int r0 = n_begin + rq * 8;
#pragma unroll
        for (int jj = 0; jj < 8; ++jj) {
            int gn = r0 + jj;
            bool ok = (gn < n_end);
            uv[jj] = ok ? U[(size_t)gn * 128 + sc] : 0.0f;
            xv[jj] = ok ? x[(size_t)gn * 128 + sc] : 0.0f;
        }
        s16x8 uh, ul, xh, xl;
#pragma unroll
        for (int jj = 0; jj < 8; ++jj) {
            unsigned short h, l;
            split_trunc(uv[jj], h, l);
            uh[jj] = (short)h; ul[jj] = (short)l;
            split_trunc(xv[jj], h, l);
            xh[jj] = (short)h; xl[jj] = (short)l;
        }
        *(s16x8*)&SB[0][0][sgran * 8] = uh;
        *(s16x8*)&SB[0][1][sgran * 8] = ul;
        *(s16x8*)&SB[0][2][sgran * 8] = xh;
        *(s16x8*)&SB[0][3][sgran * 8] = xl;
    }
    __syncthreads();

    const int nIters = (n_end - n_begin + 31) >> 5;
    for (int it = 0; it < nIters; ++it) {
        const bool more = (it + 1 < nIters);
        // ---- issue next chunk's loads (in flight during compute)
        if (more) {
            const int r0 = n_begin + (it + 1) * 32 + rq * 8;
#pragma unroll
            for (int jj = 0; jj < 8; ++jj) {
                int gn = r0 + jj;
                bool ok = (gn < n_end);
                uv[jj] = ok ? U[(size_t)gn * 128 + sc] : 0.0f;
                xv[jj] = ok ? x[(size_t)gn * 128 + sc] : 0.0f;
            }
        }

        // ---- compute from buffer it&1
        {
            const int buf = it & 1;
            s16x8 ah[2], al[2];
#pragma unroll
            for (int mi = 0; mi < 2; ++mi) {
                const int off = ((mtb + mi) * 64 + lane) * 8;
                ah[mi] = *(s16x8*)&SB[buf][0][off];
                al[mi] = *(s16x8*)&SB[buf][1][off];
            }
#pragma unroll
            for (int ni = 0; ni < 4; ++ni) {
                const int off = ((ntb + ni) * 64 + lane) * 8;
                s16x8 bh = *(s16x8*)&SB[buf][2][off];
                s16x8 bl = *(s16x8*)&SB[buf][3][off];
#pragma unroll
                for (int mi = 0; mi < 2; ++mi) {
                    acc[mi][ni] = __builtin_amdgcn_mfma_f32_16x16x32_bf16(ah[mi], bh, acc[mi][ni], 0, 0, 0);
                    acc[mi][ni] = __builtin_amdgcn_mfma_f32_16x16x32_bf16(al[mi], bh, acc[mi][ni], 0, 0, 0);
                    acc[mi][ni] = __builtin_amdgcn_mfma_f32_16x16x32_bf16(ah[mi], bl, acc[mi][ni], 0, 0, 0);
                }
            }
        }

        // ---- split + write next buffer (waits vmcnt; other waves still computing)
        if (more) {
            const int buf = (it + 1) & 1;
            s16x8 uh, ul, xh, xl;
#pragma unroll
            for (int jj = 0; jj < 8; ++jj) {
                unsigned short h, l;
                split_trunc(uv[jj], h, l);
                uh[jj] = (short)h; ul[jj] = (short)l;
                split_trunc(xv[jj], h, l);
                xh[jj] = (short)h; xl[jj] = (short)l;
            }
            *(s16x8*)&SB[buf][0][sgran * 8] = uh;
            *(s16x8*)&SB[buf][1][sgran * 8] = ul;
            *(s16x8*)&SB[buf][2][sgran * 8] = xh;
            *(s16x8*)&SB[buf][3][sgran * 8] = xl;
        }
        __syncthreads();
    }

    // ---- epilogue: partials[b][k][i]; C/D layout: col(i)=nl, row(k)=quad*4+reg
    float* p = partials + (size_t)b * 16384;
#pragma unroll
    for (int mi = 0; mi < 2; ++mi) {
#pragma unroll
        for (int reg = 0; reg < 4; ++reg) {
            int k = (mtb + mi) * 16 + quad * 4 + reg;
#pragma unroll
            for (int ni = 0; ni < 4; ++ni) {
                int i = (ntb + ni) * 16 + nl;
                p[k * 128 + i] = acc[mi][ni][reg];
            }
        }
    }
}

// ---------------- Kernel A2a (v2, float4): partial2[s][j..j+3] = sum over s-slice of b
__global__ __launch_bounds__(256) void kA2a(const float* __restrict__ partials,
                                            float* __restrict__ partial2, int nA) {
    const int jc = blockIdx.x >> 3;                 // 16 j-chunks of 1024
    const int s = blockIdx.x & 7;
    const int j = jc * 1024 + threadIdx.x * 4;
    const int per = (nA + 7) >> 3;
    int b = s * per;
    const int be = min(b + per, nA);
    f32x4 a0 = (f32x4)(0.0f), a1 = (f32x4)(0.0f);
    for (; b + 2 <= be; b += 2) {
        a0 += *(const f32x4*)&partials[(size_t)(b + 0) * 16384 + j];
        a1 += *(const f32x4*)&partials[(size_t)(b + 1) * 16384 + j];
    }
    for (; b < be; ++b) a0 += *(const f32x4*)&partials[(size_t)b * 16384 + j];
    *(f32x4*)&partial2[(size_t)s * 16384 + j] = a0 + a1;
}

// ---------------- Kernel B: mixed[o][k] = sum_i coeffs[o][k][i]*spec[k][i]
// spec[k][i] computed inline as sum_s partial2[s][k*128+i] (L2/L3-hot).
// Emits bf16 hi/lo of mixed in A-FRAGMENT order for kC1.
__global__ __launch_bounds__(256) void kB(const float* __restrict__ coeffs,
                                          const float* __restrict__ partial2,
                                          unsigned short* __restrict__ afrag_hi,
                                          unsigned short* __restrict__ afrag_lo) {
    int wave = (blockIdx.x * 256 + threadIdx.x) >> 6;   // [0, 16384)
    int lane = threadIdx.x & 63;
    int o = wave >> 7;
    int k = wave & 127;
    const int j = k * 128 + lane * 2;
    float2 p0 = *(const float2*)&partial2[j];
    float2 p1 = *(const float2*)&partial2[16384 + j];
    float2 p2 = *(const float2*)&partial2[2 * 16384 + j];
    float2 p3 = *(const float2*)&partial2[3 * 16384 + j];
    float2 p4 = *(const float2*)&partial2[4 * 16384 + j];
    float2 p5 = *(const float2*)&partial2[5 * 16384 + j];
    float2 p6 = *(const float2*)&partial2[6 * 16384 + j];
    float2 p7 = *(const float2*)&partial2[7 * 16384 + j];
    float sx = ((p0.x + p1.x) + (p2.x + p3.x)) + ((p4.x + p5.x) + (p6.x + p7.x));
    float sy = ((p0.y + p1.y) + (p2.y + p3.y)) + ((p4.y + p5.y) + (p6.y + p7.y));
    float2 c2 = *(const float2*)&coeffs[((size_t)o * 128 + k) * 128 + lane * 2];
    float v = c2.x * sx + c2.y * sy;
#pragma unroll
    for (int s = 32; s >= 1; s >>= 1) v += __shfl_xor(v, s);
    if (lane == 0) {
        unsigned short hi = f2bf(v);
        unsigned short lo = f2bf(v - bf2f(hi));
        int idx = ((o >> 4) * 4 + (k >> 5)) * 512 + (((k >> 3) & 3) * 16 + (o & 15)) * 8 + (k & 7);
        afrag_hi[idx] = hi;
        afrag_lo[idx] = lo;
    }
}

// ---------------- Kernel C1 (MFMA v2): 64n x 128o tile via bf16x2 split.
// 512 threads = 8 waves; wave w owns o in [w*16, w*16+16), all 64 n.
__global__ __launch_bounds__(512) void kC1(const float* __restrict__ U,
                                           const unsigned short* __restrict__ afrag_hi,
                                           const unsigned short* __restrict__ afrag_lo,
                                           float* __restrict__ out,
                                           float* __restrict__ m_part,
                                           float* __restrict__ l_part) {
    __shared__ unsigned short Bh[8192];   // granule*8 + j; granule = T*64 + kq*16 + ((n&15)^(T&3))
    __shared__ unsigned short Bl[8192];
    const int tid = threadIdx.x;
    const int b = blockIdx.x;
    const int n0 = b * TILE_N;
    const int lane = tid & 63;
    const int w = tid >> 6;        // wave id 0..7 -> o base w*16
    const int quad = lane >> 4;    // 0..3
    const int nl = lane & 15;      // col lane

    // ---- stage U -> bf16 hi/lo B-fragments in LDS
    {
        const int sn = tid & 63;        // row within tile
        const int k8b = tid >> 6;       // k-octet base 0..7
        const int gn = n0 + sn;
#pragma unroll
        for (int r = 0; r < 2; ++r) {
            const int k0 = (k8b + r * 8) * 8;   // 0..120, mult of 8
            float4 f0 = make_float4(0, 0, 0, 0), f1 = make_float4(0, 0, 0, 0);
            if (gn < N_PTS) {
                f0 = *(const float4*)&U[(size_t)gn * 128 + k0];
                f1 = *(const float4*)&U[(size_t)gn * 128 + k0 + 4];
            }
            float vv[8] = {f0.x, f0.y, f0.z, f0.w, f1.x, f1.y, f1.z, f1.w};
            s16x8 hh, ll;
#pragma unroll
            for (int jj = 0; jj < 8; ++jj) {
                unsigned short h, l;
                split_trunc(vv[jj], h, l);
                hh[jj] = (short)h;
                ll[jj] = (short)l;
            }
            const int T = (k0 >> 5) * 4 + (sn >> 4);   // tile region 0..31
            const int g = T * 64 + ((k0 >> 3) & 3) * 16 + ((sn & 15) ^ (T & 3));
            *(s16x8*)&Bh[g * 8] = hh;
            *(s16x8*)&Bl[g * 8] = ll;
        }
    }

    // ---- A fragments (8 coalesced 16B loads per wave; same for all blocks -> L2)
    s16x8 Ah[4], Al[4];
#pragma unroll
    for (int kc = 0; kc < 4; ++kc) {
        size_t aoff = (size_t)(w * 4 + kc) * 512 + lane * 8;
        Ah[kc] = *(const s16x8*)(afrag_hi + aoff);
        Al[kc] = *(const s16x8*)(afrag_lo + aoff);
    }

    __syncthreads();   // the only barrier

    f32x4 acc[4];
#pragma unroll
    for (int nt = 0; nt < 4; ++nt) acc[nt] = (f32x4)(0.0f);

#pragma unroll
    for (int kc = 0; kc < 4; ++kc) {
#pragma unroll
        for (int nt = 0; nt < 4; ++nt) {
            const int T = kc * 4 + nt;
            const int g = T * 64 + quad * 16 + (nl ^ (T & 3));
            s16x8 bh = *(s16x8*)&Bh[g * 8];
            s16x8 bl = *(s16x8*)&Bl[g * 8];
            acc[nt] = __builtin_amdgcn_mfma_f32_16x16x32_bf16(Ah[kc], bh, acc[nt], 0, 0, 0);
            acc[nt] = __builtin_amdgcn_mfma_f32_16x16x32_bf16(Al[kc], bh, acc[nt], 0, 0, 0);
            acc[nt] = __builtin_amdgcn_mfma_f32_16x16x32_bf16(Ah[kc], bl, acc[nt], 0, 0, 0);
        }
    }

    // ---- OOB guard (lane covers n = n0 + nt*16 + nl)
#pragma unroll
    for (int nt = 0; nt < 4; ++nt) {
        if (n0 + nt * 16 + nl >= N_PTS) {
#pragma unroll
            for (int reg = 0; reg < 4; ++reg) acc[nt][reg] = -3.4e38f;
        }
    }

    // ---- per-o max over 64 n
    float mb[4];
#pragma unroll
    for (int reg = 0; reg < 4; ++reg)
        mb[reg] = fmaxf(fmaxf(acc[0][reg], acc[1][reg]), fmaxf(acc[2][reg], acc[3][reg]));
#pragma unroll
    for (int s = 1; s < 16; s <<= 1) {
#pragma unroll
        for (int reg = 0; reg < 4; ++reg) mb[reg] = fmaxf(mb[reg], __shfl_xor(mb[reg], s));
    }

    // ---- exp in place + store unnormalized
#pragma unroll
    for (int nt = 0; nt < 4; ++nt) {
#pragma unroll
        for (int reg = 0; reg < 4; ++reg) acc[nt][reg] = __expf(acc[nt][reg] - mb[reg]);
        int gn = n0 + nt * 16 + nl;
        if (gn < N_PTS)
            *(f32x4*)&out[(size_t)gn * 128 + w * 16 + quad * 4] = acc[nt];
    }

    // ---- per-o sum
    float ls[4];
#pragma unroll
    for (int reg = 0; reg < 4; ++reg)
        ls[reg] = ((acc[0][reg] + acc[1][reg]) + (acc[2][reg] + acc[3][reg]));
#pragma unroll
    for (int s = 1; s < 16; s <<= 1) {
#pragma unroll
        for (int reg = 0; reg < 4; ++reg) ls[reg] += __shfl_xor(ls[reg], s);
    }

    if (nl == 0) {
#pragma unroll
        for (int reg = 0; reg < 4; ++reg) {
            int o = w * 16 + quad * 4 + reg;
            m_part[(size_t)o * NB1 + b] = mb[reg];
            l_part[(size_t)o * NB1 + b] = ls[reg];
        }
    }
}

// ---------------- Kernel C2: combine (m,l) over blocks; [o][b] layout -> coalesced
__global__ __launch_bounds__(256) void kC2(const float* __restrict__ m_part,
                                           const float* __restrict__ l_part,
                                           float* __restrict__ scale) {
    const int o = blockIdx.x;
    const int tid = threadIdx.x;
    const float* __restrict__ mp = m_part + (size_t)o * NB1;
    const float* __restrict__ lp = l_part + (size_t)o * NB1;
    __shared__ float sm[256];
    float m = -3.4e38f;
    for (int b = tid; b < NB1; b += 256) m = fmaxf(m, mp[b]);
    sm[tid] = m;
    __syncthreads();
    for (int s = 128; s >= 1; s >>= 1) {
        if (tid < s) sm[tid] = fmaxf(sm[tid], sm[tid + s]);
        __syncthreads();
    }
    m = sm[0];
    __syncthreads();
    float l = 0.0f;
    for (int b = tid; b < NB1; b += 256)
        l += lp[b] * __expf(mp[b] - m);
    sm[tid] = l;
    __syncthreads();
    for (int s = 128; s >= 1; s >>= 1) {
        if (tid < s) sm[tid] += sm[tid + s];
        __syncthreads();
    }
    l = sm[0];
    float inv = 1.0f / l;
    for (int b = tid; b < NB1; b += 256)
        scale[(size_t)o * NB1 + b] = __expf(mp[b] - m) * inv;
}

// ---------------- Kernel C3 (v2, zero-block fast path): out[n][o] *= scale[o][n/64]
// The logits span ~1e4-1e5, so scale[o][b] = exp(m_b - M_o)*invL underflows to
// exactly +0.0f for all but ~1 block per o-channel (this is why absmax ~ 2e-35:
// the softmax is effectively one-hot).  When ALL 128 scales of a block are
// exactly 0, out = v * 0 = +0 for every finite v >= 0 -- so we can write zeros
// WITHOUT reading out.  Bit-identical; saves ~92% of kC3's 51 MB read.
__global__ __launch_bounds__(256) void kC3(float* __restrict__ out,
                                           const float* __restrict__ scale) {
    const int b = blockIdx.x;
    const int tid = threadIdx.x;
    __shared__ float sc[128];
    __shared__ int anynz;
    if (tid == 0) anynz = 0;
    __syncthreads();
    if (tid < 128) {
        float s = scale[(size_t)tid * NB1 + b];
        sc[tid] = s;
        if (s != 0.0f) atomicOr(&anynz, 1);
    }
    __syncthreads();
    const int n0 = b * TILE_N;
    if (anynz == 0) {
        const float4 z = make_float4(0.0f, 0.0f, 0.0f, 0.0f);
#pragma unroll
        for (int r = 0; r < 8; ++r) {
            int idx = (r * 256 + tid) * 4;   // [0,8192)
            int n = idx >> 7;
            int o = idx & 127;
            int gn = n0 + n;
            if (gn < N_PTS)
                *(float4*)&out[(size_t)gn * 128 + o] = z;
        }
    } else {
#pragma unroll
        for (int r = 0; r < 8; ++r) {
            int idx = (r * 256 + tid) * 4;   // [0,8192)
            int n = idx >> 7;
            int o = idx & 127;
            int gn = n0 + n;
            if (gn < N_PTS) {
                float4 v = *(float4*)&out[(size_t)gn * 128 + o];
                v.x *= sc[o];
                v.y *= sc[o + 1];
                v.z *= sc[o + 2];
                v.w *= sc[o + 3];
                *(float4*)&out[(size_t)gn * 128 + o] = v;
            }
        }
    }
}

extern "C" void kernel_launch(void* const* d_in, const int* in_sizes, int n_in,
                              void* d_out, int out_size, void* d_ws, size_t ws_size,
                              hipStream_t stream) {
    const float* x = (const float*)d_in[0];       // (N, 128)
    const float* U = (const float*)d_in[1];       // (N, 128)
    const float* coeffs = (const float*)d_in[2];  // (128, 128, 128)
    float* out = (float*)d_out;                   // (N, 128)

    // workspace layout (float units; keep 16B alignment for frag buffers)
    float* f = (float*)d_ws;
    float* spec = f;                                    // 16384 (unused; layout keeper)
    unsigned short* afrag_hi = (unsigned short*)(f + 16384);   // 16384 bf16 = 8192 f
    unsigned short* afrag_lo = (unsigned short*)(f + 16384 + 8192);
    float* m_part = f + 16384 + 16384;                  // 128*NB1 ([o][b])
    float* l_part = m_part + (size_t)128 * NB1;
    float* scale = l_part + (size_t)128 * NB1;          // 128*NB1
    float* partial2 = scale + (size_t)128 * NB1;        // 8*16384
    float* partialsA = partial2 + 8 * 16384;
    (void)spec;

    size_t fixed_bytes = ((size_t)(16384 * 2) + (size_t)NB1 * 128 * 3 + (size_t)8 * 16384) * 4;
    int nA = 512;
    if (ws_size > fixed_bytes) {
        size_t avail = (ws_size - fixed_bytes) / 65536;   // 64KB per partial
        if ((size_t)nA > avail) nA = (int)avail;
    } else {
        nA = 1;
    }
    if (nA < 1) nA = 1;
    // chunk = multiple of 32 (kA sub-chunk) to avoid padded MFMA iterations
    int chunk = (((N_PTS + nA - 1) / nA) + 31) & ~31;
    int nB = (N_PTS + chunk - 1) / chunk;   // nB <= nA always

    kA<<<nB, 512, 0, stream>>>(U, x, partialsA, chunk);
    kA2a<<<128, 256, 0, stream>>>(partialsA, partial2, nB);
    kB<<<4096, 256, 0, stream>>>(coeffs, partial2, afrag_hi, afrag_lo);
    kC1<<<NB1, 512, 0, stream>>>(U, afrag_hi, afrag_lo, out, m_part, l_part);
    kC2<<<128, 256, 0, stream>>>(m_part, l_part, scale);
    kC3<<<NB1, 256, 0, stream>>>(out, scale);
}